// Round 7
// baseline (9276.775 us; speedup 1.0000x reference)
//
#include <hip/hip_runtime.h>

#define TT 800

typedef __attribute__((ext_vector_type(8))) short bf16x8;
typedef __attribute__((ext_vector_type(4))) float f32x4;
typedef unsigned short u16;
typedef unsigned int u32;
typedef unsigned long long u64;

constexpr int NCW = 128, NWG = 136, RT = 32;
constexpr size_t WL0A_OFF = 0;              // [2048][512] bf16 (W_hh0)
constexpr size_t WL0B_OFF = 2097152;        // [128][2048] bf16 (W_ih0^T gather)
constexpr size_t WL1_OFF  = 2621440;        // [2048][1024] bf16
constexpr size_t WLIN_OFF = 6815744;        // [128][512] bf16
constexpr size_t H0_OFF   = 6946816;        // [2][256][512] bf16
constexpr size_t H1_OFF   = 7471104;        // [2][256][512] bf16
constexpr size_t BAR_OFF  = 7995392;        // 8 tiles * 256B flags
constexpr size_t ZT_OFF   = 7997440;        // z_T [800][256] i32 = 819200
constexpr int HB = 256 * 512;
// LDS: A = 32 x 520 u16 = 33280 B; Gf = 32 x 129 f32 @33280; P @49792.
constexpr int A_ST = 520;
constexpr int G_OFF_B = 33280;
constexpr int P_OFF_B = 49792;
constexpr int LDS_BYTES = 53248;

__device__ __forceinline__ u16 f2b(float x) {
  u32 u = __float_as_uint(x);
  return (u16)((u + 0x7FFFu + ((u >> 16) & 1u)) >> 16);   // RNE fp32->bf16
}
__device__ __forceinline__ float b2f(u16 v) { return __uint_as_float(((u32)v) << 16); }
__device__ __forceinline__ float sigf(float x) { return 1.f / (1.f + __expf(-x)); }
__device__ __forceinline__ float tanh_f(float x) { float e = __expf(2.f * x); return 1.f - 2.f / (e + 1.f); }

// Producer stores stay agent-coherent (sc0 sc1, reach the coherence point).
__device__ __forceinline__ void st_coh8(u64* p, u64 v) {
  __hip_atomic_store(p, v, __ATOMIC_RELAXED, __HIP_MEMORY_SCOPE_AGENT);
}
__device__ __forceinline__ void fadd(u32* f) {
  __hip_atomic_fetch_add(f, 1u, __ATOMIC_RELAXED, __HIP_MEMORY_SCOPE_AGENT);
}
__device__ __forceinline__ void fpoll(u32* f, u32 thr) {
  while (__hip_atomic_load(f, __ATOMIC_RELAXED, __HIP_MEMORY_SCOPE_AGENT) < thr)
    __builtin_amdgcn_s_sleep(1);
}

__global__ void prep_kernel(const float* __restrict__ wih0, const float* __restrict__ whh0,
                            const float* __restrict__ wih1, const float* __restrict__ whh1,
                            const float* __restrict__ wlinf, const int* __restrict__ z,
                            u16* __restrict__ wl0a, u16* __restrict__ wl0b,
                            u16* __restrict__ wl1, u16* __restrict__ wlin,
                            int* __restrict__ zT) {
  int i = blockIdx.x * 256 + threadIdx.x;
  const int NA = 2048 * 512, NB = 128 * 2048, N1 = 2048 * 1024, N2 = 128 * 512, NZ = 800 * 256;
  if (i < NA) {
    int col = i >> 9, k = i & 511;
    wl0a[i] = f2b(whh0[col * 512 + k]);
  } else if (i < NA + NB) {
    int j = i - NA, k = j >> 11, col = j & 2047;
    wl0b[j] = f2b(wih0[col * 128 + k]);
  } else if (i < NA + NB + N1) {
    int j = i - NA - NB, col = j >> 10, k = j & 1023;
    float v = (k < 512) ? wih1[col * 512 + k] : whh1[col * 512 + (k - 512)];
    wl1[j] = f2b(v);
  } else if (i < NA + NB + N1 + N2) {
    int j = i - NA - NB - N1, col = j >> 9, k = j & 511;
    wlin[j] = f2b(wlinf[col * 512 + k]);
  } else if (i < NA + NB + N1 + N2 + NZ) {
    int j = i - NA - NB - N1 - N2, t = j >> 8, b = j & 255;
    zT[j] = z[b * TT + t];   // z_T[t][b]: per-tick tile read = 2 cache lines
  }
}

// 136 persistent WGs. ROUND-7 NUMBERING: tile co-located per XCD —
//   wg<128: compute, tile = wg&7, w = wg>>3  (XCD = wg%8 = tile).
//   wg>=128: logits for tile wg-128 (XCD = tile too).
// All 17 WGs of a tile share one XCD's L2: consumer h-reads are PLAIN CACHED
// loads after an agent-ACQUIRE fence (buffer_inv) following the flag poll —
// one L2 fill per line per XCD instead of 17 coherence-point round trips
// (round-6 FETCH showed 2.6 MB/tick of sc0sc1 misses = the critical path).
// Correct under any placement (G16): producers store h with sc0sc1 (data at
// coherence point before flag), consumers inv L1+L2 then load -> fills can
// only pull fresh data. Weights are register-pinned so the inv costs ~0.
// One flag/tile/tick (round-5 protocol): tick tau consumes h0(tau-1)
// [slot (tau-1)&1], h1(tau-2) [slot tau&1]; poll F >= 17*(tau+1).
__global__ __launch_bounds__(256, 1) void lstm_kernel(
    const float* __restrict__ bih0, const float* __restrict__ bhh0,
    const float* __restrict__ bih1, const float* __restrict__ bhh1,
    const float* __restrict__ blin,
    const int* __restrict__ zT, const int* __restrict__ nfr,
    const u16* __restrict__ wl0a, const u16* __restrict__ wl0b,
    const u16* __restrict__ wl1, const u16* __restrict__ wlin,
    u16* __restrict__ h0buf, u16* __restrict__ h1buf,
    u32* __restrict__ bars, float* __restrict__ out) {
  extern __shared__ char smem[];
  u16* A = (u16*)smem;
  float* Gf = (float*)(smem + G_OFF_B);
  float* Pm = (float*)(smem + P_OFF_B);
  float* Ps = Pm + 256;
  float* Pt = Ps + 256;
  const int wg = blockIdx.x;
  const bool isC = (wg < NCW);
  const int tile = isC ? (wg & 7) : (wg - NCW);
  const int w = isC ? (wg >> 3) : 16;
  const int tid = threadIdx.x, lane = tid & 63, wv = tid >> 6;
  const int l15 = lane & 15, l4 = lane >> 4;
  const int row0 = tile * RT;
  u32* F = bars + tile * 32;
  const f32x4 VZ = {0.f, 0.f, 0.f, 0.f};
  const int rC = tid >> 3, u0C = (tid & 7) * 4;   // cell mapping
  const int cuL = tid & 31, rgL = tid >> 5;       // logits softmax mapping

  float c0s[4] = {0, 0, 0, 0}, c1s[4] = {0, 0, 0, 0};
  float accN = 0.f, nflv = 0.f;
  float bias0c[2], bias1c[2], biasLc[2];
  bf16x8 bq0R[32];                  // L0 W_hh0: 128 reg
  bf16x8 bq1R[64];                  // L1: 256 reg (AGPR half)
  bf16x8 wlR[32];                   // logits path only

  if (isC) {
#pragma unroll
    for (int cb = 0; cb < 2; ++cb) {
      int col = wv * 512 + w * 32 + cb * 16 + l15;
      bias0c[cb] = bih0[col] + bhh0[col];
      bias1c[cb] = bih1[col] + bhh1[col];
      const u16* b0 = wl0a + (size_t)col * 512 + l4 * 8;
#pragma unroll
      for (int kb = 0; kb < 16; ++kb) bq0R[cb * 16 + kb] = *(const bf16x8*)(b0 + kb * 32);
      const u16* b1 = wl1 + (size_t)col * 1024 + l4 * 8;
#pragma unroll
      for (int kb = 0; kb < 32; ++kb) bq1R[cb * 32 + kb] = *(const bf16x8*)(b1 + kb * 32);
    }
  } else {
#pragma unroll
    for (int cb = 0; cb < 2; ++cb) {
      int colV = wv * 32 + cb * 16 + l15;
      biasLc[cb] = blin[colV];
      const u16* bL = wlin + (size_t)colV * 512 + l4 * 8;
#pragma unroll
      for (int kb = 0; kb < 16; ++kb) wlR[cb * 16 + kb] = *(const bf16x8*)(bL + kb * 32);
    }
    if (rgL == 0) nflv = (float)nfr[row0 + cuL];
  }

  if (isC && w == 0) {
    u64* z0 = (u64*)(h0buf + HB + row0 * 512);
    u64* z1 = (u64*)(h1buf + row0 * 512);
    u64* z2 = (u64*)(h1buf + HB + row0 * 512);
    for (int k = tid; k < 2048; k += 256) { st_coh8(z0 + k, 0); st_coh8(z1 + k, 0); st_coh8(z2 + k, 0); }
  }
  __syncthreads();
  if (tid == 0) fadd(F);

  auto ldA = [&](int rb, int kb) {
    return *(const bf16x8*)(A + (rb * 16 + l15) * A_ST + kb * 32 + l4 * 8);
  };

#pragma unroll 1
  for (int tau = 0; tau <= TT + 1; ++tau) {
    if (tid == 0) {
      fpoll(F, 17u * (u32)(tau + 1));
      __builtin_amdgcn_fence(__ATOMIC_ACQUIRE, "agent");  // buffer_inv: L1+L2
    }
    __syncthreads();  // B1: inputs published AND caches invalidated
    const u16* h0src = h0buf + ((tau + 1) & 1) * HB + row0 * 512;
    const u16* h1src = h1buf + (tau & 1) * HB + row0 * 512;
    const bool l0act = isC && (tau < TT);
    const bool l1act = isC && (tau >= 1 && tau <= TT);

    if (isC) {
      // ---- stage h0(tau-1): plain cached 16B loads (L2-shared) -> A ----
      if (tau <= TT) {
        bf16x8 t16[8];
#pragma unroll
        for (int c = 0; c < 8; ++c) {
          int li = c * 256 + tid, row = li >> 6, cc = li & 63;
          t16[c] = *(const bf16x8*)(h0src + row * 512 + cc * 8);
        }
#pragma unroll
        for (int c = 0; c < 8; ++c) {
          int li = c * 256 + tid, row = li >> 6, cc = li & 63;
          *(bf16x8*)(A + row * A_ST + cc * 8) = t16[c];
        }
      }
      // issue h1(tau-2) batch1 (rows 0..15), in flight across L0/L1p1 MFMA
      bf16x8 ha[4];
      if (l1act) {
#pragma unroll
        for (int c = 0; c < 4; ++c) {
          int li = c * 256 + tid, row = li >> 6, cc = li & 63;
          ha[c] = *(const bf16x8*)(h1src + row * 512 + cc * 8);
        }
      }
      __syncthreads();  // B2: A(h0) ready

      f32x4 acc0[2][2] = {{VZ, VZ}, {VZ, VZ}};
      f32x4 acc1[2][2] = {{VZ, VZ}, {VZ, VZ}};
      u64 gvq[4] = {0, 0, 0, 0};
      if (l0act && tau >= 1) {
        // early-issue: z + W_ih0 row gather, latency hidden under MFMA
        int zrC = zT[(tau - 1) * 256 + row0 + rC];
        const u16* gb = wl0b + (size_t)zrC * 2048 + w * 32 + u0C;
#pragma unroll
        for (int g = 0; g < 4; ++g) gvq[g] = *(const u64*)(gb + g * 512);
      }
      if (l0act) {
#pragma unroll
        for (int kb = 0; kb < 16; ++kb) {
          bf16x8 a0 = ldA(0, kb), a1 = ldA(1, kb);
#pragma unroll
          for (int cb = 0; cb < 2; ++cb) {
            acc0[0][cb] = __builtin_amdgcn_mfma_f32_16x16x32_bf16(a0, bq0R[cb * 16 + kb], acc0[0][cb], 0, 0, 0);
            acc0[1][cb] = __builtin_amdgcn_mfma_f32_16x16x32_bf16(a1, bq0R[cb * 16 + kb], acc0[1][cb], 0, 0, 0);
          }
        }
      }
      if (l1act) {
        // L1 part 1: K 0..511 (h0(tau-1)) from A, weights in registers
#pragma unroll
        for (int kb = 0; kb < 16; ++kb) {
          bf16x8 a0 = ldA(0, kb), a1 = ldA(1, kb);
#pragma unroll
          for (int cb = 0; cb < 2; ++cb) {
            acc1[0][cb] = __builtin_amdgcn_mfma_f32_16x16x32_bf16(a0, bq1R[cb * 32 + kb], acc1[0][cb], 0, 0, 0);
            acc1[1][cb] = __builtin_amdgcn_mfma_f32_16x16x32_bf16(a1, bq1R[cb * 32 + kb], acc1[1][cb], 0, 0, 0);
          }
        }
      }
      if (l0act) {
#pragma unroll
        for (int rb = 0; rb < 2; ++rb)
#pragma unroll
          for (int cb = 0; cb < 2; ++cb)
#pragma unroll
            for (int q = 0; q < 4; ++q)
              Gf[(rb * 16 + l4 * 4 + q) * 129 + wv * 32 + cb * 16 + l15] = acc0[rb][cb][q] + bias0c[cb];
      }
      __syncthreads();  // B3: Gf(L0) ready AND all A(h0) reads done

      bf16x8 ha2[4];
      if (l1act) {
#pragma unroll
        for (int c = 0; c < 4; ++c) {
          int li = (c + 4) * 256 + tid, row = li >> 6, cc = li & 63;
          ha2[c] = *(const bf16x8*)(h1src + row * 512 + cc * 8);
        }
      }
      if (l0act) {
        // ---- cell0: gates + gathered W_ih0 row + update, 8B coherent store ----
        float g4[4][4];
#pragma unroll
        for (int g = 0; g < 4; ++g)
#pragma unroll
          for (int j = 0; j < 4; ++j) g4[g][j] = Gf[rC * 129 + g * 32 + u0C + j];
        if (tau >= 1) {
#pragma unroll
          for (int g = 0; g < 4; ++g)
#pragma unroll
            for (int j = 0; j < 4; ++j) g4[g][j] += b2f((u16)(gvq[g] >> (16 * j)));
        }
        u64 pk = 0;
#pragma unroll
        for (int j = 0; j < 4; ++j) {
          float cn = sigf(g4[1][j]) * c0s[j] + sigf(g4[0][j]) * tanh_f(g4[2][j]);
          float hn = sigf(g4[3][j]) * tanh_f(cn);
          c0s[j] = cn;
          pk |= ((u64)f2b(hn)) << (16 * j);
        }
        u16* h0w = h0buf + (tau & 1) * HB + row0 * 512;
        st_coh8((u64*)(h0w + rC * 512 + w * 32 + u0C), pk);
      }
      if (l1act) {
#pragma unroll
        for (int c = 0; c < 4; ++c) {
          int li = c * 256 + tid, row = li >> 6, cc = li & 63;
          *(bf16x8*)(A + row * A_ST + cc * 8) = ha[c];
        }
#pragma unroll
        for (int c = 0; c < 4; ++c) {
          int li = (c + 4) * 256 + tid, row = li >> 6, cc = li & 63;
          *(bf16x8*)(A + row * A_ST + cc * 8) = ha2[c];
        }
      }
      __syncthreads();  // B4: A(h1) ready AND cell0 Gf reads done

      if (l1act) {
#pragma unroll
        for (int kb = 16; kb < 32; ++kb) {
          bf16x8 a0 = ldA(0, kb - 16), a1 = ldA(1, kb - 16);
#pragma unroll
          for (int cb = 0; cb < 2; ++cb) {
            acc1[0][cb] = __builtin_amdgcn_mfma_f32_16x16x32_bf16(a0, bq1R[cb * 32 + kb], acc1[0][cb], 0, 0, 0);
            acc1[1][cb] = __builtin_amdgcn_mfma_f32_16x16x32_bf16(a1, bq1R[cb * 32 + kb], acc1[1][cb], 0, 0, 0);
          }
        }
#pragma unroll
        for (int rb = 0; rb < 2; ++rb)
#pragma unroll
          for (int cb = 0; cb < 2; ++cb)
#pragma unroll
            for (int q = 0; q < 4; ++q)
              Gf[(rb * 16 + l4 * 4 + q) * 129 + wv * 32 + cb * 16 + l15] = acc1[rb][cb][q] + bias1c[cb];
      }
      __syncthreads();  // B5: Gf(L1) ready

      if (l1act) {
        float g4[4][4];
#pragma unroll
        for (int g = 0; g < 4; ++g)
#pragma unroll
          for (int j = 0; j < 4; ++j) g4[g][j] = Gf[rC * 129 + g * 32 + u0C + j];
        u64 pk = 0;
#pragma unroll
        for (int j = 0; j < 4; ++j) {
          float cn = sigf(g4[1][j]) * c1s[j] + sigf(g4[0][j]) * tanh_f(g4[2][j]);
          float hn = sigf(g4[3][j]) * tanh_f(cn);
          c1s[j] = cn;
          pk |= ((u64)f2b(hn)) << (16 * j);
        }
        u16* h1w = h1buf + ((tau + 1) & 1) * HB + row0 * 512;
        st_coh8((u64*)(h1w + rC * 512 + w * 32 + u0C), pk);
      }
      __syncthreads();  // B6: vmcnt(0) drain => coherent stores visible
      if (tid == 0) fadd(F);
    } else {
      // ---------------- logits WG: NLL(tau-2) ----------------
      const bool lgact = (tau >= 2);
      if (lgact) {
        bf16x8 t16[8];
#pragma unroll
        for (int c = 0; c < 8; ++c) {
          int li = c * 256 + tid, row = li >> 6, cc = li & 63;
          t16[c] = *(const bf16x8*)(h1src + row * 512 + cc * 8);
        }
#pragma unroll
        for (int c = 0; c < 8; ++c) {
          int li = c * 256 + tid, row = li >> 6, cc = li & 63;
          *(bf16x8*)(A + row * A_ST + cc * 8) = t16[c];
        }
      }
      __syncthreads();  // B2: staged (loads retired)
      if (tid == 0) fadd(F);  // early release: WAR obligation met
      if (lgact) {
        f32x4 accL[2][2] = {{VZ, VZ}, {VZ, VZ}};
#pragma unroll
        for (int kb = 0; kb < 16; ++kb) {
          bf16x8 a0 = ldA(0, kb), a1 = ldA(1, kb);
#pragma unroll
          for (int cb = 0; cb < 2; ++cb) {
            accL[0][cb] = __builtin_amdgcn_mfma_f32_16x16x32_bf16(a0, wlR[cb * 16 + kb], accL[0][cb], 0, 0, 0);
            accL[1][cb] = __builtin_amdgcn_mfma_f32_16x16x32_bf16(a1, wlR[cb * 16 + kb], accL[1][cb], 0, 0, 0);
          }
        }
#pragma unroll
        for (int rb = 0; rb < 2; ++rb)
#pragma unroll
          for (int cb = 0; cb < 2; ++cb)
#pragma unroll
            for (int q = 0; q < 4; ++q)
              Gf[(rb * 16 + l4 * 4 + q) * 129 + wv * 32 + cb * 16 + l15] = accL[rb][cb][q] + biasLc[cb];
      }
      __syncthreads();  // B3: Gf ready
      if (lgact) {
        int t2 = tau - 2;
        int r = cuL, k = rgL;
        float vloc[16], mloc = -3.4e38f;
#pragma unroll
        for (int j = 0; j < 16; ++j) {
          vloc[j] = Gf[r * 129 + k * 16 + j];
          mloc = fmaxf(mloc, vloc[j]);
        }
        Pm[r * 8 + k] = mloc;
        __syncthreads();
        float mrow = Pm[r * 8];
#pragma unroll
        for (int j = 1; j < 8; ++j) mrow = fmaxf(mrow, Pm[r * 8 + j]);
        int zr = zT[t2 * 256 + row0 + r];
        float sloc = 0.f, tloc = 0.f;
#pragma unroll
        for (int j = 0; j < 16; ++j) {
          sloc += __expf(vloc[j] - mrow);
          tloc += (k * 16 + j == zr) ? vloc[j] : 0.f;
        }
        Ps[r * 8 + k] = sloc; Pt[r * 8 + k] = tloc;
        __syncthreads();
        if (k == 0) {
          float s = 0.f, tv = 0.f;
#pragma unroll
          for (int j = 0; j < 8; ++j) { s += Ps[r * 8 + j]; tv += Pt[r * 8 + j]; }
          if ((float)t2 < nflv) accN += mrow + __logf(s) - tv;
        }
      } else {
        __syncthreads(); __syncthreads();
      }
    }
  }

  if (!isC && rgL == 0) out[row0 + cuL] = accN * (1.0f / TT);
}

extern "C" void kernel_launch(void* const* d_in, const int* in_sizes, int n_in,
                              void* d_out, int out_size, void* d_ws, size_t ws_size,
                              hipStream_t stream) {
  const float* wih0 = (const float*)d_in[0];
  const float* whh0 = (const float*)d_in[1];
  const float* bih0 = (const float*)d_in[2];
  const float* bhh0 = (const float*)d_in[3];
  const float* wih1 = (const float*)d_in[4];
  const float* whh1 = (const float*)d_in[5];
  const float* bih1 = (const float*)d_in[6];
  const float* bhh1 = (const float*)d_in[7];
  const float* wlinf = (const float*)d_in[8];
  const float* blin = (const float*)d_in[9];
  const int* z = (const int*)d_in[10];
  const int* nfr = (const int*)d_in[11];
  float* out = (float*)d_out;
  char* ws = (char*)d_ws;
  u16* wl0a = (u16*)(ws + WL0A_OFF);
  u16* wl0b = (u16*)(ws + WL0B_OFF);
  u16* wl1 = (u16*)(ws + WL1_OFF);
  u16* wlin = (u16*)(ws + WLIN_OFF);
  u16* h0buf = (u16*)(ws + H0_OFF);
  u16* h1buf = (u16*)(ws + H1_OFF);
  u32* bars = (u32*)(ws + BAR_OFF);
  int* zT = (int*)(ws + ZT_OFF);

  hipMemsetAsync(ws + BAR_OFF, 0, 2048, stream);
  const int NTOT = 2048 * 512 + 128 * 2048 + 2048 * 1024 + 128 * 512 + 800 * 256;
  prep_kernel<<<dim3((NTOT + 255) / 256), dim3(256), 0, stream>>>(
      wih0, whh0, wih1, whh1, wlinf, z, wl0a, wl0b, wl1, wlin, zT);
  lstm_kernel<<<dim3(NWG), dim3(256), LDS_BYTES, stream>>>(
      bih0, bhh0, bih1, bhh1, blin, zT, nfr, wl0a, wl0b, wl1, wlin, h0buf, h1buf, bars, out);
}